// Round 1
// baseline (239.493 us; speedup 1.0000x reference)
//
#include <hip/hip_runtime.h>
#include <math.h>

#define BLK 256

__global__ __launch_bounds__(BLK) void wasserstein_kernel(
    const float* __restrict__ loc1,   const float* __restrict__ scale1,
    const float* __restrict__ rot1,   const float* __restrict__ loc2,
    const float* __restrict__ scale2, const float* __restrict__ rot2,
    float* __restrict__ out)
{
    // LDS staging: per-block slabs, all global reads as coalesced float4.
    __shared__ float smem[BLK * 30];
    float* sL1 = smem;             // BLK*3
    float* sS1 = smem + BLK * 3;   // BLK*3
    float* sR1 = smem + BLK * 6;   // BLK*9
    float* sL2 = smem + BLK * 15;  // BLK*3
    float* sS2 = smem + BLK * 18;  // BLK*3
    float* sR2 = smem + BLK * 21;  // BLK*9

    const int tid = threadIdx.x;
    const long long blockStart = (long long)blockIdx.x * BLK;

    // Stage a slab of n4 float4s from global (elemsPerItem floats per element).
    // Global base offset = blockStart*elemsPerItem floats; 16B-aligned since
    // BLK*3*4 = 3072 B and BLK*9*4 = 9216 B are both multiples of 16.
    {
        const float4* g4;
        float4* l4;

        g4 = reinterpret_cast<const float4*>(loc1 + blockStart * 3);
        l4 = reinterpret_cast<float4*>(sL1);
        for (int i = tid; i < BLK * 3 / 4; i += BLK) l4[i] = g4[i];

        g4 = reinterpret_cast<const float4*>(scale1 + blockStart * 3);
        l4 = reinterpret_cast<float4*>(sS1);
        for (int i = tid; i < BLK * 3 / 4; i += BLK) l4[i] = g4[i];

        g4 = reinterpret_cast<const float4*>(rot1 + blockStart * 9);
        l4 = reinterpret_cast<float4*>(sR1);
        for (int i = tid; i < BLK * 9 / 4; i += BLK) l4[i] = g4[i];

        g4 = reinterpret_cast<const float4*>(loc2 + blockStart * 3);
        l4 = reinterpret_cast<float4*>(sL2);
        for (int i = tid; i < BLK * 3 / 4; i += BLK) l4[i] = g4[i];

        g4 = reinterpret_cast<const float4*>(scale2 + blockStart * 3);
        l4 = reinterpret_cast<float4*>(sS2);
        for (int i = tid; i < BLK * 3 / 4; i += BLK) l4[i] = g4[i];

        g4 = reinterpret_cast<const float4*>(rot2 + blockStart * 9);
        l4 = reinterpret_cast<float4*>(sR2);
        for (int i = tid; i < BLK * 9 / 4; i += BLK) l4[i] = g4[i];
    }
    __syncthreads();

    // ---- per-thread math (all from LDS; stride 3/9 reads are conflict-free) ----
    const float l1x = sL1[tid * 3 + 0], l1y = sL1[tid * 3 + 1], l1z = sL1[tid * 3 + 2];
    const float l2x = sL2[tid * 3 + 0], l2y = sL2[tid * 3 + 1], l2z = sL2[tid * 3 + 2];
    const float dx = l1x - l2x, dy = l1y - l2y, dz = l1z - l2z;
    const float loc_diff2 = dx * dx + dy * dy + dz * dz;

    const float s1a = sS1[tid * 3 + 0], s1b = sS1[tid * 3 + 1], s1c = sS1[tid * 3 + 2];
    const float s2a = sS2[tid * 3 + 0], s2b = sS2[tid * 3 + 1], s2c = sS2[tid * 3 + 2];

    float R1[9], R2[9];
#pragma unroll
    for (int k = 0; k < 9; ++k) R1[k] = sR1[tid * 9 + k];
#pragma unroll
    for (int k = 0; k < 9; ++k) R2[k] = sR2[tid * 9 + k];

    // M2 = R2 diag(s2) R2^T  (symmetric; 6 unique entries)
    // M2[i][k] = sum_j R2[i][j]*s2[j]*R2[k][j]
    const float m00 = s2a * R2[0] * R2[0] + s2b * R2[1] * R2[1] + s2c * R2[2] * R2[2];
    const float m01 = s2a * R2[0] * R2[3] + s2b * R2[1] * R2[4] + s2c * R2[2] * R2[5];
    const float m02 = s2a * R2[0] * R2[6] + s2b * R2[1] * R2[7] + s2c * R2[2] * R2[8];
    const float m11 = s2a * R2[3] * R2[3] + s2b * R2[4] * R2[4] + s2c * R2[5] * R2[5];
    const float m12 = s2a * R2[3] * R2[6] + s2b * R2[4] * R2[7] + s2c * R2[5] * R2[8];
    const float m22 = s2a * R2[6] * R2[6] + s2b * R2[7] * R2[7] + s2c * R2[8] * R2[8];

    // A = M2 * R1   (A[j][l] = sum_k M2[j][k] * R1[k][l])
    float A[9];
    A[0] = m00 * R1[0] + m01 * R1[3] + m02 * R1[6];
    A[1] = m00 * R1[1] + m01 * R1[4] + m02 * R1[7];
    A[2] = m00 * R1[2] + m01 * R1[5] + m02 * R1[8];
    A[3] = m01 * R1[0] + m11 * R1[3] + m12 * R1[6];
    A[4] = m01 * R1[1] + m11 * R1[4] + m12 * R1[7];
    A[5] = m01 * R1[2] + m11 * R1[5] + m12 * R1[8];
    A[6] = m02 * R1[0] + m12 * R1[3] + m22 * R1[6];
    A[7] = m02 * R1[1] + m12 * R1[4] + m22 * R1[7];
    A[8] = m02 * R1[2] + m12 * R1[5] + m22 * R1[8];

    // T = R1^T * A   (T[i][l] = sum_j R1[j][i] * A[j][l])
    float T[9];
    T[0] = R1[0] * A[0] + R1[3] * A[3] + R1[6] * A[6];
    T[1] = R1[0] * A[1] + R1[3] * A[4] + R1[6] * A[7];
    T[2] = R1[0] * A[2] + R1[3] * A[5] + R1[6] * A[8];
    T[3] = R1[1] * A[0] + R1[4] * A[3] + R1[7] * A[6];
    T[4] = R1[1] * A[1] + R1[4] * A[4] + R1[7] * A[7];
    T[5] = R1[1] * A[2] + R1[4] * A[5] + R1[7] * A[8];
    T[6] = R1[2] * A[0] + R1[5] * A[3] + R1[8] * A[6];
    T[7] = R1[2] * A[1] + R1[5] * A[4] + R1[8] * A[7];
    T[8] = R1[2] * A[2] + R1[5] * A[5] + R1[8] * A[8];

    // E = diag(sqrt(s1)) T diag(sqrt(s1)), symmetrized
    const float sq0 = sqrtf(s1a), sq1 = sqrtf(s1b), sq2 = sqrtf(s1c);
    const float e00 = s1a * T[0];
    const float e11 = s1b * T[4];
    const float e22 = s1c * T[8];
    const float e01 = 0.5f * sq0 * sq1 * (T[1] + T[3]);
    const float e02 = 0.5f * sq0 * sq2 * (T[2] + T[6]);
    const float e12 = 0.5f * sq1 * sq2 * (T[5] + T[7]);

    // Analytic eigenvalues of symmetric 3x3 (trigonometric / Smith's method)
    const float q  = (e00 + e11 + e22) * (1.0f / 3.0f);
    const float p1 = e01 * e01 + e02 * e02 + e12 * e12;
    const float d0 = e00 - q, d1 = e11 - q, d2 = e22 - q;
    const float p2 = d0 * d0 + d1 * d1 + d2 * d2 + 2.0f * p1;

    float trace_sqrt;
    if (p2 > 1e-24f) {
        const float p   = sqrtf(p2 * (1.0f / 6.0f));
        const float inv = 1.0f / p;
        const float b00 = d0 * inv, b11 = d1 * inv, b22 = d2 * inv;
        const float b01 = e01 * inv, b02 = e02 * inv, b12 = e12 * inv;
        float detB = b00 * (b11 * b22 - b12 * b12)
                   - b01 * (b01 * b22 - b12 * b02)
                   + b02 * (b01 * b12 - b11 * b02);
        float r = 0.5f * detB;
        r = fminf(fmaxf(r, -1.0f), 1.0f);
        const float phi  = acosf(r) * (1.0f / 3.0f);
        const float twop = 2.0f * p;
        const float eig1 = q + twop * cosf(phi);
        const float eig3 = q + twop * cosf(phi + 2.0943951023931953f); // + 2*pi/3
        const float eig2 = 3.0f * q - eig1 - eig3;
        trace_sqrt = sqrtf(fabsf(eig1)) + sqrtf(fabsf(eig2)) + sqrtf(fabsf(eig3));
    } else {
        trace_sqrt = 3.0f * sqrtf(fabsf(q));
    }

    float cov_w = (s1a + s1b + s1c) + (s2a + s2b + s2c) - 2.0f * trace_sqrt;
    cov_w = fmaxf(cov_w, 0.0f);
    out[blockStart + tid] = sqrtf(loc_diff2 + cov_w);
}

extern "C" void kernel_launch(void* const* d_in, const int* in_sizes, int n_in,
                              void* d_out, int out_size, void* d_ws, size_t ws_size,
                              hipStream_t stream) {
    const float* loc1   = (const float*)d_in[0];
    const float* scale1 = (const float*)d_in[1];
    const float* rot1   = (const float*)d_in[2];
    const float* loc2   = (const float*)d_in[3];
    const float* scale2 = (const float*)d_in[4];
    const float* rot2   = (const float*)d_in[5];
    float* out = (float*)d_out;

    const int B = in_sizes[0] / 3;   // 2097152; divisible by BLK
    const int grid = B / BLK;

    wasserstein_kernel<<<grid, BLK, 0, stream>>>(loc1, scale1, rot1,
                                                 loc2, scale2, rot2, out);
}